// Round 1
// baseline (468.301 us; speedup 1.0000x reference)
//
#include <hip/hip_runtime.h>

// Problem constants (fixed by the reference)
#define E_DIM 1024
#define NH    16
#define HDIM  64
#define BB    2
#define LSEQ  2048
#define MTOT  (BB*LSEQ)   // 4096 tokens

typedef float  f32x4  __attribute__((ext_vector_type(4)));
typedef __bf16 bf16x8 __attribute__((ext_vector_type(8)));
typedef unsigned int   u32x4 __attribute__((ext_vector_type(4)));
typedef unsigned short u16x4 __attribute__((ext_vector_type(4)));
typedef unsigned short u16x8 __attribute__((ext_vector_type(8)));

union U16 {           // 16-byte fragment: 8 bf16
    u32x4  u4;
    bf16x8 b;
};

__device__ inline unsigned short f2bf(float f) {
    union { __bf16 h; unsigned short u; } x;
    x.h = (__bf16)f;   // RNE via v_cvt (compiler handles packing — m240)
    return x.u;
}

// ---------------- fp32 -> bf16 bulk convert ----------------
__global__ __launch_bounds__(256) void convert_bf16(
    const float* __restrict__ in, unsigned short* __restrict__ out, int n)
{
    int i = (blockIdx.x * 256 + threadIdx.x) * 4;
    int stride = gridDim.x * 256 * 4;
    for (; i < n; i += stride) {
        f32x4 v = *(const f32x4*)(in + i);
        u16x4 o = { f2bf(v.x), f2bf(v.y), f2bf(v.z), f2bf(v.w) };
        *(u16x4*)(out + i) = o;
    }
}

// ---------------- W [K][N] f32  ->  Wt [N][K] bf16 ----------------
__global__ __launch_bounds__(256) void transpose_w(
    const float* __restrict__ W, unsigned short* __restrict__ Wt)
{
    __shared__ unsigned short tile[64][80];   // pad: row stride 160B, 16B-aligned
    int n0 = blockIdx.x * 64, k0 = blockIdx.y * 64;
    int t = threadIdx.x;
#pragma unroll
    for (int i = 0; i < 4; i++) {
        int idx = i * 256 + t;             // 1024 float4 chunks
        int kr = idx >> 4, nc = (idx & 15) * 4;
        f32x4 v = *(const f32x4*)(W + (size_t)(k0 + kr) * E_DIM + n0 + nc);
        u16x4 o = { f2bf(v.x), f2bf(v.y), f2bf(v.z), f2bf(v.w) };
        *(u16x4*)&tile[kr][nc] = o;
    }
    __syncthreads();
#pragma unroll
    for (int i = 0; i < 2; i++) {
        int idx = i * 256 + t;             // 512 8-elem chunks
        int nr = idx >> 3, kc = (idx & 7) * 8;
        union { unsigned short s[8]; u16x8 v; } pack;
#pragma unroll
        for (int j = 0; j < 8; j++) pack.s[j] = tile[kc + j][nr];
        *(u16x8*)(Wt + (size_t)(n0 + nr) * E_DIM + k0 + kc) = pack.v;
    }
}

// ---------------- V [bh][L][64] -> Vt [bh][64][L] (bf16) ----------------
__global__ __launch_bounds__(256) void transpose_v(
    const unsigned short* __restrict__ V, unsigned short* __restrict__ Vt)
{
    __shared__ unsigned short tile[64][80];
    int l0 = blockIdx.x * 64;
    int bh = blockIdx.y;
    const unsigned short* Vb = V + (size_t)bh * LSEQ * HDIM;
    unsigned short* Vtb = Vt + (size_t)bh * HDIM * LSEQ;
    int t = threadIdx.x;
#pragma unroll
    for (int i = 0; i < 2; i++) {
        int idx = i * 256 + t;
        int lr = idx >> 3, dc = (idx & 7) * 8;
        *(u16x8*)&tile[lr][dc] = *(const u16x8*)(Vb + (size_t)(l0 + lr) * HDIM + dc);
    }
    __syncthreads();
#pragma unroll
    for (int i = 0; i < 2; i++) {
        int idx = i * 256 + t;
        int dr = idx >> 3, lc = (idx & 7) * 8;
        union { unsigned short s[8]; u16x8 v; } pack;
#pragma unroll
        for (int j = 0; j < 8; j++) pack.s[j] = tile[lc + j][dr];
        *(u16x8*)(Vtb + (size_t)dr * LSEQ + l0 + lc) = pack.v;
    }
}

// ---------------- GEMM: C[m][n] = sum_k A[m][k]*Bt[n][k] + bias[n] ----------------
// A: [M][K] bf16 row-major, Bt: [N][K] bf16 row-major.
// mode 0: outF[m*N+n] = v            (fp32, final output)
// mode 1: outBf[b,h,l,hd] = bf16(v*scale)   (head-major QKV projections)
// 128x128 tile, BK=64, 4 waves, 16x16x32 bf16 MFMA, T2 XOR-swizzled LDS.
__global__ __launch_bounds__(256) void gemm_bt(
    const unsigned short* __restrict__ A, const unsigned short* __restrict__ Bt,
    const float* __restrict__ bias, unsigned short* __restrict__ outBf,
    float* __restrict__ outF, int M, int N, int K, float scale, int mode)
{
    __shared__ unsigned short Al[128 * 64];
    __shared__ unsigned short Bl[128 * 64];
    int t = threadIdx.x;
    int lane = t & 63, w = t >> 6;
    int qc = lane & 15, kg = lane >> 4;
    int m0 = blockIdx.x * 128, n0 = blockIdx.y * 128;
    int wr = (w >> 1) * 64, wc = (w & 1) * 64;

    f32x4 acc[4][4];
#pragma unroll
    for (int i = 0; i < 4; i++)
#pragma unroll
        for (int j = 0; j < 4; j++)
            acc[i][j] = {0.f, 0.f, 0.f, 0.f};

    int nk = K >> 6;
    for (int kt = 0; kt < nk; kt++) {
        int k0 = kt << 6;
        __syncthreads();   // protect LDS from previous iteration's readers
#pragma unroll
        for (int i = 0; i < 4; i++) {
            int idx = i * 256 + t;
            int row = idx >> 3, col = (idx & 7) << 3;       // 8-elem chunks
            int sc_ = col ^ ((row & 7) << 3);               // T2 swizzle (elems)
            *(u32x4*)&Al[row * 64 + sc_] =
                *(const u32x4*)(A + (size_t)(m0 + row) * K + k0 + col);
            *(u32x4*)&Bl[row * 64 + sc_] =
                *(const u32x4*)(Bt + (size_t)(n0 + row) * K + k0 + col);
        }
        __syncthreads();
#pragma unroll
        for (int k2 = 0; k2 < 2; k2++) {
            U16 af[4], bg[4];
#pragma unroll
            for (int mi = 0; mi < 4; mi++) {
                int row = wr + mi * 16 + qc;
                int col = (k2 * 32 + kg * 8) ^ ((row & 7) << 3);
                af[mi].u4 = *(const u32x4*)&Al[row * 64 + col];
            }
#pragma unroll
            for (int ni = 0; ni < 4; ni++) {
                int row = wc + ni * 16 + qc;
                int col = (k2 * 32 + kg * 8) ^ ((row & 7) << 3);
                bg[ni].u4 = *(const u32x4*)&Bl[row * 64 + col];
            }
#pragma unroll
            for (int mi = 0; mi < 4; mi++)
#pragma unroll
                for (int ni = 0; ni < 4; ni++)
                    acc[mi][ni] = __builtin_amdgcn_mfma_f32_16x16x32_bf16(
                        af[mi].b, bg[ni].b, acc[mi][ni], 0, 0, 0);
        }
    }

    // Epilogue. D layout: col n = lane&15, row m = (lane>>4)*4 + r  [m89]
#pragma unroll
    for (int ni = 0; ni < 4; ni++) {
        int n = n0 + wc + ni * 16 + qc;
        float bval = bias[n];
#pragma unroll
        for (int mi = 0; mi < 4; mi++) {
#pragma unroll
            for (int r = 0; r < 4; r++) {
                int m = m0 + wr + mi * 16 + kg * 4 + r;
                float v = acc[mi][ni][r] + bval;
                if (mode == 0) {
                    outF[(size_t)m * N + n] = v;
                } else {
                    int b = m >> 11, l = m & (LSEQ - 1);
                    int h = n >> 6, hd = n & 63;
                    outBf[(((size_t)(b * NH + h)) * LSEQ + l) * HDIM + hd] =
                        f2bf(v * scale);
                }
            }
        }
    }
}

// ---------------- causal flash attention ----------------
// Qh/Kh: [bh][L][64] bf16 (Q pre-scaled by log2e/8). Vt: [bh][64][L] bf16.
// Ctx: [b][l][E] bf16. Grid (L/64, B*H), 4 independent waves of 16 q-rows.
__global__ __launch_bounds__(256) void attn_causal(
    const unsigned short* __restrict__ Qh, const unsigned short* __restrict__ Kh,
    const unsigned short* __restrict__ Vt, unsigned short* __restrict__ Ctx)
{
    __shared__ unsigned short Pl[4][16][88];  // per-wave P buffer; stride 176B
    int qb = blockIdx.x, bh = blockIdx.y;
    int t = threadIdx.x;
    int w = t >> 6, lane = t & 63;
    int qc = lane & 15, kg = lane >> 4;
    int q0 = qb * 64 + w * 16;

    const unsigned short* Qb = Qh + (size_t)bh * LSEQ * HDIM;
    const unsigned short* Kb = Kh + (size_t)bh * LSEQ * HDIM;
    const unsigned short* Vb = Vt + (size_t)bh * HDIM * LSEQ;

    // Q fragments, resident for whole kernel (A-op: row=lane&15, k=(lane>>4)*8+j)
    U16 aq0, aq1;
    aq0.u4 = *(const u32x4*)(Qb + (size_t)(q0 + qc) * HDIM + kg * 8);
    aq1.u4 = *(const u32x4*)(Qb + (size_t)(q0 + qc) * HDIM + 32 + kg * 8);

    f32x4 ctx[4];
#pragma unroll
    for (int df = 0; df < 4; df++) ctx[df] = {0.f, 0.f, 0.f, 0.f};
    float mrun[4] = {-1e30f, -1e30f, -1e30f, -1e30f};
    float lrun[4] = {0.f, 0.f, 0.f, 0.f};

    int kv_end = q0 + 16;                 // causal: kv <= q0+15 needed
    for (int kv0 = 0; kv0 < kv_end; kv0 += 64) {
        // ---- S = Q K^T (pre-scaled so softmax uses exp2) ----
        f32x4 s[4];
#pragma unroll
        for (int f = 0; f < 4; f++) {
            U16 kf0, kf1;   // B-op: col(kv)=lane&15, k(d)=(lane>>4)*8+j
            kf0.u4 = *(const u32x4*)(Kb + (size_t)(kv0 + f * 16 + qc) * HDIM + kg * 8);
            kf1.u4 = *(const u32x4*)(Kb + (size_t)(kv0 + f * 16 + qc) * HDIM + 32 + kg * 8);
            f32x4 z = {0.f, 0.f, 0.f, 0.f};
            z = __builtin_amdgcn_mfma_f32_16x16x32_bf16(aq0.b, kf0.b, z, 0, 0, 0);
            z = __builtin_amdgcn_mfma_f32_16x16x32_bf16(aq1.b, kf1.b, z, 0, 0, 0);
            s[f] = z;
        }
        // ---- causal mask (only tiles overlapping the diagonal) ----
        if (kv0 + 63 > q0) {
#pragma unroll
            for (int f = 0; f < 4; f++) {
                int kvj = kv0 + f * 16 + qc;
#pragma unroll
                for (int r = 0; r < 4; r++) {
                    int qi = q0 + kg * 4 + r;
                    if (kvj > qi) s[f][r] = -1e30f;
                }
            }
        }
        // ---- online softmax; row m = kg*4+r lives in 16-lane group ----
#pragma unroll
        for (int r = 0; r < 4; r++) {
            float tm = fmaxf(fmaxf(s[0][r], s[1][r]), fmaxf(s[2][r], s[3][r]));
            tm = fmaxf(tm, __shfl_xor(tm, 1));
            tm = fmaxf(tm, __shfl_xor(tm, 2));
            tm = fmaxf(tm, __shfl_xor(tm, 4));
            tm = fmaxf(tm, __shfl_xor(tm, 8));
            float mn = fmaxf(mrun[r], tm);
            float sc = exp2f(mrun[r] - mn);
            mrun[r] = mn;
            float e0 = exp2f(s[0][r] - mn);
            float e1 = exp2f(s[1][r] - mn);
            float e2 = exp2f(s[2][r] - mn);
            float e3 = exp2f(s[3][r] - mn);
            float rs = (e0 + e1) + (e2 + e3);
            rs += __shfl_xor(rs, 1);
            rs += __shfl_xor(rs, 2);
            rs += __shfl_xor(rs, 4);
            rs += __shfl_xor(rs, 8);
            lrun[r] = lrun[r] * sc + rs;
#pragma unroll
            for (int df = 0; df < 4; df++) ctx[df][r] *= sc;
            int m = kg * 4 + r;
            Pl[w][m][qc]      = f2bf(e0);
            Pl[w][m][16 + qc] = f2bf(e1);
            Pl[w][m][32 + qc] = f2bf(e2);
            Pl[w][m][48 + qc] = f2bf(e3);
        }
        // ---- ctx += P V  (P re-read in A-op layout; V^T rows contiguous) ----
#pragma unroll
        for (int k2 = 0; k2 < 2; k2++) {
            U16 ap;
            ap.u4 = *(const u32x4*)&Pl[w][qc][k2 * 32 + kg * 8];
#pragma unroll
            for (int df = 0; df < 4; df++) {
                U16 vf;
                vf.u4 = *(const u32x4*)(Vb + (size_t)(df * 16 + qc) * LSEQ +
                                        kv0 + k2 * 32 + kg * 8);
                ctx[df] = __builtin_amdgcn_mfma_f32_16x16x32_bf16(
                    ap.b, vf.b, ctx[df], 0, 0, 0);
            }
        }
    }
    // ---- normalize + store ctx[b][q][h*64+d] ----
    int b = bh >> 4, h = bh & 15;
    unsigned short* Cb = Ctx + ((size_t)b * LSEQ) * E_DIM + h * HDIM;
#pragma unroll
    for (int r = 0; r < 4; r++) {
        float inv = 1.f / lrun[r];
        int q = q0 + kg * 4 + r;
#pragma unroll
        for (int df = 0; df < 4; df++) {
            Cb[(size_t)q * E_DIM + df * 16 + qc] = f2bf(ctx[df][r] * inv);
        }
    }
}

// ---------------- launcher ----------------
extern "C" void kernel_launch(void* const* d_in, const int* in_sizes, int n_in,
                              void* d_out, int out_size, void* d_ws, size_t ws_size,
                              hipStream_t stream)
{
    (void)in_sizes; (void)n_in; (void)out_size; (void)ws_size;
    const float* query = (const float*)d_in[0];
    const float* key_  = (const float*)d_in[1];
    const float* value = (const float*)d_in[2];
    // d_in[3] key_padding_mask (all False), d_in[4] attn_mask (causal) — semantics
    // are fixed by the problem; causality implemented directly.
    const float* Wq = (const float*)d_in[5];
    const float* bq = (const float*)d_in[6];
    const float* Wk = (const float*)d_in[7];
    const float* bk = (const float*)d_in[8];
    const float* Wv = (const float*)d_in[9];
    const float* bv = (const float*)d_in[10];
    const float* Wo = (const float*)d_in[11];
    const float* bo = (const float*)d_in[12];
    float* out = (float*)d_out;

    char* ws = (char*)d_ws;
    const size_t MB = 1024 * 1024;
    unsigned short* Xq  = (unsigned short*)(ws + 0 * MB);
    unsigned short* Xk  = (unsigned short*)(ws + 8 * MB);
    unsigned short* Xv  = (unsigned short*)(ws + 16 * MB);
    unsigned short* Wqt = (unsigned short*)(ws + 24 * MB);
    unsigned short* Wkt = (unsigned short*)(ws + 26 * MB);
    unsigned short* Wvt = (unsigned short*)(ws + 28 * MB);
    unsigned short* Wot = (unsigned short*)(ws + 30 * MB);
    unsigned short* Qh  = (unsigned short*)(ws + 32 * MB);
    unsigned short* Kh  = (unsigned short*)(ws + 40 * MB);
    unsigned short* Vh  = (unsigned short*)(ws + 48 * MB);
    unsigned short* Vtp = (unsigned short*)(ws + 56 * MB);
    unsigned short* Ctx = (unsigned short*)(ws + 0 * MB);  // reuse Xq (dead after Q proj)

    const int nElem = MTOT * E_DIM;
    convert_bf16<<<dim3(1024), 256, 0, stream>>>(query, Xq, nElem);
    convert_bf16<<<dim3(1024), 256, 0, stream>>>(key_,  Xk, nElem);
    convert_bf16<<<dim3(1024), 256, 0, stream>>>(value, Xv, nElem);

    dim3 gw(16, 16);
    transpose_w<<<gw, 256, 0, stream>>>(Wq, Wqt);
    transpose_w<<<gw, 256, 0, stream>>>(Wk, Wkt);
    transpose_w<<<gw, 256, 0, stream>>>(Wv, Wvt);
    transpose_w<<<gw, 256, 0, stream>>>(Wo, Wot);

    dim3 gg(32, 8);
    const float SCALE_Q = 0.18033688011112042f;  // log2(e) / sqrt(HD)=8
    gemm_bt<<<gg, 256, 0, stream>>>(Xq, Wqt, bq, Qh, nullptr,
                                    MTOT, E_DIM, E_DIM, SCALE_Q, 1);
    gemm_bt<<<gg, 256, 0, stream>>>(Xk, Wkt, bk, Kh, nullptr,
                                    MTOT, E_DIM, E_DIM, 1.0f, 1);
    gemm_bt<<<gg, 256, 0, stream>>>(Xv, Wvt, bv, Vh, nullptr,
                                    MTOT, E_DIM, E_DIM, 1.0f, 1);

    transpose_v<<<dim3(32, 32), 256, 0, stream>>>(Vh, Vtp);

    attn_causal<<<dim3(32, 32), 256, 0, stream>>>(Qh, Kh, Vtp, Ctx);

    gemm_bt<<<gg, 256, 0, stream>>>(Ctx, Wot, bo, nullptr, out,
                                    MTOT, E_DIM, E_DIM, 1.0f, 0);
}

// Round 2
// 372.692 us; speedup vs baseline: 1.2565x; 1.2565x over previous
//
#include <hip/hip_runtime.h>

// Problem constants (fixed by the reference)
#define E_DIM 1024
#define NH    16
#define HDIM  64
#define BB    2
#define LSEQ  2048
#define MTOT  (BB*LSEQ)   // 4096 tokens

typedef float  f32x4  __attribute__((ext_vector_type(4)));
typedef __bf16 bf16x8 __attribute__((ext_vector_type(8)));
typedef unsigned int   u32x4 __attribute__((ext_vector_type(4)));
typedef unsigned short u16x4 __attribute__((ext_vector_type(4)));
typedef unsigned short u16x8 __attribute__((ext_vector_type(8)));

union U16 {           // 16-byte fragment: 8 bf16
    u32x4  u4;
    bf16x8 b;
};

__device__ inline unsigned short f2bf(float f) {
    union { __bf16 h; unsigned short u; } x;
    x.h = (__bf16)f;
    return x.u;
}

// async global->LDS, 16B per lane. LDS dest is wave-uniform base + lane*16.
__device__ __forceinline__ void gload_lds16(const unsigned short* g, unsigned short* l) {
    __builtin_amdgcn_global_load_lds(
        (const __attribute__((address_space(1))) void*)g,
        (__attribute__((address_space(3))) void*)l, 16, 0, 0);
}

// ---------------- fp32 -> bf16 bulk convert ----------------
__global__ __launch_bounds__(256) void convert_bf16(
    const float* __restrict__ in, unsigned short* __restrict__ out, int n)
{
    int i = (blockIdx.x * 256 + threadIdx.x) * 4;
    int stride = gridDim.x * 256 * 4;
    for (; i < n; i += stride) {
        f32x4 v = *(const f32x4*)(in + i);
        u16x4 o = { f2bf(v.x), f2bf(v.y), f2bf(v.z), f2bf(v.w) };
        *(u16x4*)(out + i) = o;
    }
}

// ---------------- W [K][N] f32  ->  Wt [N][K] bf16 ----------------
__global__ __launch_bounds__(256) void transpose_w(
    const float* __restrict__ W, unsigned short* __restrict__ Wt)
{
    __shared__ unsigned short tile[64][80];
    int n0 = blockIdx.x * 64, k0 = blockIdx.y * 64;
    int t = threadIdx.x;
#pragma unroll
    for (int i = 0; i < 4; i++) {
        int idx = i * 256 + t;
        int kr = idx >> 4, nc = (idx & 15) * 4;
        f32x4 v = *(const f32x4*)(W + (size_t)(k0 + kr) * E_DIM + n0 + nc);
        u16x4 o = { f2bf(v.x), f2bf(v.y), f2bf(v.z), f2bf(v.w) };
        *(u16x4*)&tile[kr][nc] = o;
    }
    __syncthreads();
#pragma unroll
    for (int i = 0; i < 2; i++) {
        int idx = i * 256 + t;
        int nr = idx >> 3, kc = (idx & 7) * 8;
        union { unsigned short s[8]; u16x8 v; } pack;
#pragma unroll
        for (int j = 0; j < 8; j++) pack.s[j] = tile[kc + j][nr];
        *(u16x8*)(Wt + (size_t)(n0 + nr) * E_DIM + k0 + kc) = pack.v;
    }
}

// ---------------- V [bh][L][64] -> Vt [bh][64][L] (bf16) ----------------
__global__ __launch_bounds__(256) void transpose_v(
    const unsigned short* __restrict__ V, unsigned short* __restrict__ Vt)
{
    __shared__ unsigned short tile[64][80];
    int l0 = blockIdx.x * 64;
    int bh = blockIdx.y;
    const unsigned short* Vb = V + (size_t)bh * LSEQ * HDIM;
    unsigned short* Vtb = Vt + (size_t)bh * HDIM * LSEQ;
    int t = threadIdx.x;
#pragma unroll
    for (int i = 0; i < 2; i++) {
        int idx = i * 256 + t;
        int lr = idx >> 3, dc = (idx & 7) * 8;
        *(u16x8*)&tile[lr][dc] = *(const u16x8*)(Vb + (size_t)(l0 + lr) * HDIM + dc);
    }
    __syncthreads();
#pragma unroll
    for (int i = 0; i < 2; i++) {
        int idx = i * 256 + t;
        int dr = idx >> 3, lc = (idx & 7) * 8;
        union { unsigned short s[8]; u16x8 v; } pack;
#pragma unroll
        for (int j = 0; j < 8; j++) pack.s[j] = tile[lc + j][dr];
        *(u16x8*)(Vtb + (size_t)dr * LSEQ + l0 + lc) = pack.v;
    }
}

// ---------------- GEMM (m97 structure): C = A * Bt^T + bias ----------------
// A: [M][K] bf16, Bt: [N][K] bf16. 128x128 tile, BK=64, 4 waves,
// global_load_lds width-16 staging into linear LDS, 16x16x32 bf16 MFMA.
__global__ __launch_bounds__(256) void gemm_bt(
    const unsigned short* __restrict__ A, const unsigned short* __restrict__ Bt,
    const float* __restrict__ bias, unsigned short* __restrict__ outBf,
    float* __restrict__ outF, int M, int N, int K, float scale, int mode)
{
    __shared__ unsigned short Al[128 * 64];
    __shared__ unsigned short Bl[128 * 64];
    int t = threadIdx.x;
    int lane = t & 63, w = t >> 6;
    int qc = lane & 15, kg = lane >> 4;
    int m0 = blockIdx.x * 128, n0 = blockIdx.y * 128;
    int wr = (w >> 1) * 64, wc = (w & 1) * 64;

    // staging: wave w covers rows [w*32, w*32+32) of each tile, 4 instrs of 8 rows
    int srow = w * 32 + (lane >> 3);
    int scol = (lane & 7) * 8;
    const unsigned short* Ag = A + (size_t)(m0 + srow) * K + scol;
    const unsigned short* Bg = Bt + (size_t)(n0 + srow) * K + scol;
    unsigned short* Asl = &Al[(w * 32) * 64];
    unsigned short* Bsl = &Bl[(w * 32) * 64];

    f32x4 acc[4][4];
#pragma unroll
    for (int i = 0; i < 4; i++)
#pragma unroll
        for (int j = 0; j < 4; j++)
            acc[i][j] = {0.f, 0.f, 0.f, 0.f};

    int nk = K >> 6;
    for (int kt = 0; kt < nk; kt++) {
        const unsigned short* Ak = Ag + (kt << 6);
        const unsigned short* Bk = Bg + (kt << 6);
        __syncthreads();   // protect LDS from previous iteration's readers
#pragma unroll
        for (int i = 0; i < 4; i++) {
            gload_lds16(Ak + (size_t)i * 8 * K, Asl + i * 8 * 64);
            gload_lds16(Bk + (size_t)i * 8 * K, Bsl + i * 8 * 64);
        }
        __syncthreads();   // drains vmcnt: staged data visible
#pragma unroll
        for (int k2 = 0; k2 < 2; k2++) {
            U16 af[4], bg[4];
#pragma unroll
            for (int mi = 0; mi < 4; mi++)
                af[mi].u4 = *(const u32x4*)&Al[(wr + mi * 16 + qc) * 64 + k2 * 32 + kg * 8];
#pragma unroll
            for (int ni = 0; ni < 4; ni++)
                bg[ni].u4 = *(const u32x4*)&Bl[(wc + ni * 16 + qc) * 64 + k2 * 32 + kg * 8];
#pragma unroll
            for (int mi = 0; mi < 4; mi++)
#pragma unroll
                for (int ni = 0; ni < 4; ni++)
                    acc[mi][ni] = __builtin_amdgcn_mfma_f32_16x16x32_bf16(
                        af[mi].b, bg[ni].b, acc[mi][ni], 0, 0, 0);
        }
    }

    // Epilogue. D layout: col n = lane&15, row m = (lane>>4)*4 + r  [m89]
#pragma unroll
    for (int ni = 0; ni < 4; ni++) {
        int n = n0 + wc + ni * 16 + qc;
        float bval = bias[n];
#pragma unroll
        for (int mi = 0; mi < 4; mi++) {
#pragma unroll
            for (int r = 0; r < 4; r++) {
                int m = m0 + wr + mi * 16 + kg * 4 + r;
                float v = acc[mi][ni][r] + bval;
                if (mode == 0) {
                    outF[(size_t)m * N + n] = v;
                } else {
                    int b = m >> 11, l = m & (LSEQ - 1);
                    int h = n >> 6, hd = n & 63;
                    outBf[(((size_t)(b * NH + h)) * LSEQ + l) * HDIM + hd] =
                        f2bf(v * scale);
                }
            }
        }
    }
}

// ---------------- causal flash attention (balanced + pipelined) ----------------
// Qh/Kh: [bh][L][64] bf16 (Q pre-scaled by log2e/8). Vt: [bh][64][L] bf16.
// Grid (16, B*H). Block = 4 waves. Pass 0: q-tile x, pass 1: q-tile 31-x
// (wave order flipped) -> every block does exactly 33 kv-tiles of work.
__global__ __launch_bounds__(256) void attn_causal(
    const unsigned short* __restrict__ Qh, const unsigned short* __restrict__ Kh,
    const unsigned short* __restrict__ Vt, unsigned short* __restrict__ Ctx)
{
    __shared__ unsigned short Pl[4][16][88];  // per-wave P buffer; stride 176B
    int bh = blockIdx.y;
    int t = threadIdx.x;
    int w = t >> 6, lane = t & 63;
    int qc = lane & 15, kg = lane >> 4;

    const unsigned short* Qb = Qh + (size_t)bh * LSEQ * HDIM;
    // hoisted per-lane bases (strength reduction: per-tile addr = base + uniform)
    const unsigned short* Kp = Kh + (size_t)bh * LSEQ * HDIM + qc * HDIM + kg * 8;
    const unsigned short* Vbase = Vt + (size_t)bh * HDIM * LSEQ + qc * LSEQ + kg * 8;
    int b = bh >> 4, h = bh & 15;
    unsigned short* Cb = Ctx + ((size_t)b * LSEQ) * E_DIM + h * HDIM;

    unsigned short* Pw = &Pl[w][0][0];
    unsigned short* Pst = Pw + (kg * 4) * 88 + qc;        // store: row kg*4+r, col f*16+qc
    const unsigned short* Pld = Pw + qc * 88 + kg * 8;    // load: A-op row qc, k = kg*8

    for (int pass = 0; pass < 2; pass++) {
        int qtile = pass ? (31 - (int)blockIdx.x) : (int)blockIdx.x;
        int wv = pass ? (3 - w) : w;
        int q0 = qtile * 64 + wv * 16;

        // Q fragments (A-op: row=lane&15, k=(lane>>4)*8+j)
        U16 aq0, aq1;
        aq0.u4 = *(const u32x4*)(Qb + (size_t)(q0 + qc) * HDIM + kg * 8);
        aq1.u4 = *(const u32x4*)(Qb + (size_t)(q0 + qc) * HDIM + 32 + kg * 8);

        f32x4 ctx[4];
#pragma unroll
        for (int df = 0; df < 4; df++) ctx[df] = {0.f, 0.f, 0.f, 0.f};
        float mrun[4] = {-1e30f, -1e30f, -1e30f, -1e30f};
        float lrun[4] = {0.f, 0.f, 0.f, 0.f};

        int nt = (q0 + 16 + 63) >> 6;   // 64-wide kv tiles

        // preload K tile 0 (B-op: col(kv)=lane&15, k(d)=(lane>>4)*8+j)
        U16 kf[4][2];
#pragma unroll
        for (int f = 0; f < 4; f++) {
            kf[f][0].u4 = *(const u32x4*)(Kp + f * 16 * HDIM);
            kf[f][1].u4 = *(const u32x4*)(Kp + f * 16 * HDIM + 32);
        }

        for (int tt = 0; tt < nt; tt++) {
            int kv0 = tt << 6;
            // ---- S = Q K^T ----
            f32x4 s[4];
#pragma unroll
            for (int f = 0; f < 4; f++) {
                f32x4 z = {0.f, 0.f, 0.f, 0.f};
                z = __builtin_amdgcn_mfma_f32_16x16x32_bf16(aq0.b, kf[f][0].b, z, 0, 0, 0);
                z = __builtin_amdgcn_mfma_f32_16x16x32_bf16(aq1.b, kf[f][1].b, z, 0, 0, 0);
                s[f] = z;
            }
            // ---- V loads for this tile (independent of softmax; hide latency) ----
            U16 vf[2][4];
#pragma unroll
            for (int k2 = 0; k2 < 2; k2++)
#pragma unroll
                for (int df = 0; df < 4; df++)
                    vf[k2][df].u4 = *(const u32x4*)(Vbase + (size_t)df * 16 * LSEQ +
                                                    kv0 + k2 * 32);
            // ---- K prefetch for next tile ----
            if (tt + 1 < nt) {
                const unsigned short* Kt = Kp + (size_t)(kv0 + 64) * HDIM;
#pragma unroll
                for (int f = 0; f < 4; f++) {
                    kf[f][0].u4 = *(const u32x4*)(Kt + f * 16 * HDIM);
                    kf[f][1].u4 = *(const u32x4*)(Kt + f * 16 * HDIM + 32);
                }
            }
            // ---- causal mask (diagonal tiles only) ----
            if (kv0 + 63 > q0) {
#pragma unroll
                for (int f = 0; f < 4; f++) {
                    int kvj = kv0 + f * 16 + qc;
#pragma unroll
                    for (int r = 0; r < 4; r++) {
                        int qi = q0 + kg * 4 + r;
                        if (kvj > qi) s[f][r] = -1e30f;
                    }
                }
            }
            // ---- online softmax; row m = kg*4+r spans 16 lanes (qc) ----
#pragma unroll
            for (int r = 0; r < 4; r++) {
                float tm = fmaxf(fmaxf(s[0][r], s[1][r]), fmaxf(s[2][r], s[3][r]));
                tm = fmaxf(tm, __shfl_xor(tm, 1));
                tm = fmaxf(tm, __shfl_xor(tm, 2));
                tm = fmaxf(tm, __shfl_xor(tm, 4));
                tm = fmaxf(tm, __shfl_xor(tm, 8));
                float mn = fmaxf(mrun[r], tm);
                float sc = exp2f(mrun[r] - mn);
                mrun[r] = mn;
                float e0 = exp2f(s[0][r] - mn);
                float e1 = exp2f(s[1][r] - mn);
                float e2 = exp2f(s[2][r] - mn);
                float e3 = exp2f(s[3][r] - mn);
                float rs = (e0 + e1) + (e2 + e3);
                rs += __shfl_xor(rs, 1);
                rs += __shfl_xor(rs, 2);
                rs += __shfl_xor(rs, 4);
                rs += __shfl_xor(rs, 8);
                lrun[r] = lrun[r] * sc + rs;
#pragma unroll
                for (int df = 0; df < 4; df++) ctx[df][r] *= sc;
                Pst[r * 88]      = f2bf(e0);
                Pst[r * 88 + 16] = f2bf(e1);
                Pst[r * 88 + 32] = f2bf(e2);
                Pst[r * 88 + 48] = f2bf(e3);
            }
            // ---- ctx += P V ----
#pragma unroll
            for (int k2 = 0; k2 < 2; k2++) {
                U16 ap;
                ap.u4 = *(const u32x4*)(Pld + k2 * 32);
#pragma unroll
                for (int df = 0; df < 4; df++)
                    ctx[df] = __builtin_amdgcn_mfma_f32_16x16x32_bf16(
                        ap.b, vf[k2][df].b, ctx[df], 0, 0, 0);
            }
        }
        // ---- normalize + store ctx[b][q][h*64+d] ----
#pragma unroll
        for (int r = 0; r < 4; r++) {
            float inv = 1.f / lrun[r];
            int q = q0 + kg * 4 + r;
#pragma unroll
            for (int df = 0; df < 4; df++) {
                Cb[(size_t)q * E_DIM + df * 16 + qc] = f2bf(ctx[df][r] * inv);
            }
        }
    }
}

// ---------------- launcher ----------------
extern "C" void kernel_launch(void* const* d_in, const int* in_sizes, int n_in,
                              void* d_out, int out_size, void* d_ws, size_t ws_size,
                              hipStream_t stream)
{
    (void)in_sizes; (void)n_in; (void)out_size; (void)ws_size;
    const float* query = (const float*)d_in[0];
    const float* key_  = (const float*)d_in[1];
    const float* value = (const float*)d_in[2];
    const float* Wq = (const float*)d_in[5];
    const float* bq = (const float*)d_in[6];
    const float* Wk = (const float*)d_in[7];
    const float* bk = (const float*)d_in[8];
    const float* Wv = (const float*)d_in[9];
    const float* bv = (const float*)d_in[10];
    const float* Wo = (const float*)d_in[11];
    const float* bo = (const float*)d_in[12];
    float* out = (float*)d_out;

    char* ws = (char*)d_ws;
    const size_t MB = 1024 * 1024;
    unsigned short* Xq  = (unsigned short*)(ws + 0 * MB);
    unsigned short* Xk  = (unsigned short*)(ws + 8 * MB);
    unsigned short* Xv  = (unsigned short*)(ws + 16 * MB);
    unsigned short* Wqt = (unsigned short*)(ws + 24 * MB);
    unsigned short* Wkt = (unsigned short*)(ws + 26 * MB);
    unsigned short* Wvt = (unsigned short*)(ws + 28 * MB);
    unsigned short* Wot = (unsigned short*)(ws + 30 * MB);
    unsigned short* Qh  = (unsigned short*)(ws + 32 * MB);
    unsigned short* Kh  = (unsigned short*)(ws + 40 * MB);
    unsigned short* Vh  = (unsigned short*)(ws + 48 * MB);
    unsigned short* Vtp = (unsigned short*)(ws + 56 * MB);
    unsigned short* Ctx = (unsigned short*)(ws + 0 * MB);  // reuse Xq

    const int nElem = MTOT * E_DIM;
    convert_bf16<<<dim3(1024), 256, 0, stream>>>(query, Xq, nElem);
    convert_bf16<<<dim3(1024), 256, 0, stream>>>(key_,  Xk, nElem);
    convert_bf16<<<dim3(1024), 256, 0, stream>>>(value, Xv, nElem);

    dim3 gw(16, 16);
    transpose_w<<<gw, 256, 0, stream>>>(Wq, Wqt);
    transpose_w<<<gw, 256, 0, stream>>>(Wk, Wkt);
    transpose_w<<<gw, 256, 0, stream>>>(Wv, Wvt);
    transpose_w<<<gw, 256, 0, stream>>>(Wo, Wot);

    dim3 gg(32, 8);
    const float SCALE_Q = 0.18033688011112042f;  // log2(e) / sqrt(HD)=8
    gemm_bt<<<gg, 256, 0, stream>>>(Xq, Wqt, bq, Qh, nullptr,
                                    MTOT, E_DIM, E_DIM, SCALE_Q, 1);
    gemm_bt<<<gg, 256, 0, stream>>>(Xk, Wkt, bk, Kh, nullptr,
                                    MTOT, E_DIM, E_DIM, 1.0f, 1);
    gemm_bt<<<gg, 256, 0, stream>>>(Xv, Wvt, bv, Vh, nullptr,
                                    MTOT, E_DIM, E_DIM, 1.0f, 1);

    transpose_v<<<dim3(32, 32), 256, 0, stream>>>(Vh, Vtp);

    attn_causal<<<dim3(16, 32), 256, 0, stream>>>(Qh, Kh, Vtp, Ctx);

    gemm_bt<<<gg, 256, 0, stream>>>(Ctx, Wot, bo, nullptr, out,
                                    MTOT, E_DIM, E_DIM, 1.0f, 0);
}

// Round 3
// 315.994 us; speedup vs baseline: 1.4820x; 1.1794x over previous
//
#include <hip/hip_runtime.h>

// Problem constants (fixed by the reference)
#define E_DIM 1024
#define NH    16
#define HDIM  64
#define BB    2
#define LSEQ  2048
#define MTOT  (BB*LSEQ)   // 4096 tokens

typedef float  f32x4  __attribute__((ext_vector_type(4)));
typedef __bf16 bf16x8 __attribute__((ext_vector_type(8)));
typedef unsigned int   u32x4 __attribute__((ext_vector_type(4)));
typedef unsigned short u16x4 __attribute__((ext_vector_type(4)));
typedef unsigned short u16x8 __attribute__((ext_vector_type(8)));

union U16 {           // 16-byte fragment: 8 bf16
    u32x4  u4;
    bf16x8 b;
};

__device__ inline unsigned short f2bf(float f) {
    union { __bf16 h; unsigned short u; } x;
    x.h = (__bf16)f;
    return x.u;
}

__device__ __forceinline__ float fexp2(float x) {
#if __has_builtin(__builtin_amdgcn_exp2f)
    return __builtin_amdgcn_exp2f(x);   // single v_exp_f32
#else
    return exp2f(x);
#endif
}

// async global->LDS, 16B per lane. LDS dest is wave-uniform base + lane*16.
__device__ __forceinline__ void gload_lds16(const unsigned short* g, unsigned short* l) {
    __builtin_amdgcn_global_load_lds(
        (const __attribute__((address_space(1))) void*)g,
        (__attribute__((address_space(3))) void*)l, 16, 0, 0);
}

// ---------------- fp32 -> bf16 bulk convert, 3 tensors in one launch ----------------
__global__ __launch_bounds__(256) void convert3(
    const float* __restrict__ q, const float* __restrict__ k, const float* __restrict__ v,
    unsigned short* __restrict__ Xq, unsigned short* __restrict__ Xk,
    unsigned short* __restrict__ Xv, int n)
{
    int z = blockIdx.y;
    const float* in = z == 0 ? q : (z == 1 ? k : v);
    unsigned short* out = z == 0 ? Xq : (z == 1 ? Xk : Xv);
    int i = (blockIdx.x * 256 + threadIdx.x) * 4;
    int stride = gridDim.x * 256 * 4;
    for (; i < n; i += stride) {
        f32x4 val = *(const f32x4*)(in + i);
        u16x4 o = { f2bf(val.x), f2bf(val.y), f2bf(val.z), f2bf(val.w) };
        *(u16x4*)(out + i) = o;
    }
}

// ---------------- W [K][N] f32 -> Wt [N][K] bf16, 4 weights in one launch ----------------
__global__ __launch_bounds__(256) void transpose_w4(
    const float* __restrict__ Wq, const float* __restrict__ Wk,
    const float* __restrict__ Wv, const float* __restrict__ Wo,
    unsigned short* __restrict__ Wqt, unsigned short* __restrict__ Wkt,
    unsigned short* __restrict__ Wvt, unsigned short* __restrict__ Wot)
{
    int z = blockIdx.z;
    const float* W = z == 0 ? Wq : (z == 1 ? Wk : (z == 2 ? Wv : Wo));
    unsigned short* Wt = z == 0 ? Wqt : (z == 1 ? Wkt : (z == 2 ? Wvt : Wot));
    __shared__ unsigned short tile[64][80];
    int n0 = blockIdx.x * 64, k0 = blockIdx.y * 64;
    int t = threadIdx.x;
#pragma unroll
    for (int i = 0; i < 4; i++) {
        int idx = i * 256 + t;
        int kr = idx >> 4, nc = (idx & 15) * 4;
        f32x4 val = *(const f32x4*)(W + (size_t)(k0 + kr) * E_DIM + n0 + nc);
        u16x4 o = { f2bf(val.x), f2bf(val.y), f2bf(val.z), f2bf(val.w) };
        *(u16x4*)&tile[kr][nc] = o;
    }
    __syncthreads();
#pragma unroll
    for (int i = 0; i < 2; i++) {
        int idx = i * 256 + t;
        int nr = idx >> 3, kc = (idx & 7) * 8;
        union { unsigned short s[8]; u16x8 v; } pack;
#pragma unroll
        for (int j = 0; j < 8; j++) pack.s[j] = tile[kc + j][nr];
        *(u16x8*)(Wt + (size_t)(n0 + nr) * E_DIM + k0 + kc) = pack.v;
    }
}

// ---------------- V [bh][L][64] -> Vt [bh][64][L] (bf16) ----------------
__global__ __launch_bounds__(256) void transpose_v(
    const unsigned short* __restrict__ V, unsigned short* __restrict__ Vt)
{
    __shared__ unsigned short tile[64][80];
    int l0 = blockIdx.x * 64;
    int bh = blockIdx.y;
    const unsigned short* Vb = V + (size_t)bh * LSEQ * HDIM;
    unsigned short* Vtb = Vt + (size_t)bh * HDIM * LSEQ;
    int t = threadIdx.x;
#pragma unroll
    for (int i = 0; i < 2; i++) {
        int idx = i * 256 + t;
        int lr = idx >> 3, dc = (idx & 7) * 8;
        *(u16x8*)&tile[lr][dc] = *(const u16x8*)(Vb + (size_t)(l0 + lr) * HDIM + dc);
    }
    __syncthreads();
#pragma unroll
    for (int i = 0; i < 2; i++) {
        int idx = i * 256 + t;
        int dr = idx >> 3, lc = (idx & 7) * 8;
        union { unsigned short s[8]; u16x8 v; } pack;
#pragma unroll
        for (int j = 0; j < 8; j++) pack.s[j] = tile[lc + j][dr];
        *(u16x8*)(Vtb + (size_t)dr * LSEQ + l0 + lc) = pack.v;
    }
}

// ---------------- batched QKV projection GEMM (z = 0,1,2) ----------------
// out[b,h,l,hd] = bf16((X @ Wt^T + bias) * scale), 128x128 tile, BK=64, m97 staging.
__global__ __launch_bounds__(256) void gemm_qkv(
    const unsigned short* __restrict__ Xq, const unsigned short* __restrict__ Xk,
    const unsigned short* __restrict__ Xv,
    const unsigned short* __restrict__ Wqt, const unsigned short* __restrict__ Wkt,
    const unsigned short* __restrict__ Wvt,
    const float* __restrict__ bqp, const float* __restrict__ bkp, const float* __restrict__ bvp,
    unsigned short* __restrict__ Qh, unsigned short* __restrict__ Kh,
    unsigned short* __restrict__ Vh, float scaleQ)
{
    int z = blockIdx.z;
    const unsigned short* A  = z == 0 ? Xq  : (z == 1 ? Xk  : Xv);
    const unsigned short* Bt = z == 0 ? Wqt : (z == 1 ? Wkt : Wvt);
    const float* bias        = z == 0 ? bqp : (z == 1 ? bkp : bvp);
    unsigned short* out      = z == 0 ? Qh  : (z == 1 ? Kh  : Vh);
    float scale              = z == 0 ? scaleQ : 1.0f;

    __shared__ unsigned short Al[128 * 64];
    __shared__ unsigned short Bl[128 * 64];
    int t = threadIdx.x;
    int lane = t & 63, w = t >> 6;
    int qc = lane & 15, kg = lane >> 4;
    int m0 = blockIdx.x * 128, n0 = blockIdx.y * 128;
    int wr = (w >> 1) * 64, wc = (w & 1) * 64;

    int srow = w * 32 + (lane >> 3);
    int scol = (lane & 7) * 8;
    const unsigned short* Ag = A + (size_t)(m0 + srow) * E_DIM + scol;
    const unsigned short* Bg = Bt + (size_t)(n0 + srow) * E_DIM + scol;
    unsigned short* Asl = &Al[(w * 32) * 64];
    unsigned short* Bsl = &Bl[(w * 32) * 64];

    f32x4 acc[4][4];
#pragma unroll
    for (int i = 0; i < 4; i++)
#pragma unroll
        for (int j = 0; j < 4; j++)
            acc[i][j] = {0.f, 0.f, 0.f, 0.f};

    for (int kt = 0; kt < E_DIM / 64; kt++) {
        const unsigned short* Ak = Ag + (kt << 6);
        const unsigned short* Bk = Bg + (kt << 6);
        __syncthreads();
#pragma unroll
        for (int i = 0; i < 4; i++) {
            gload_lds16(Ak + (size_t)i * 8 * E_DIM, Asl + i * 8 * 64);
            gload_lds16(Bk + (size_t)i * 8 * E_DIM, Bsl + i * 8 * 64);
        }
        __syncthreads();
#pragma unroll
        for (int k2 = 0; k2 < 2; k2++) {
            U16 af[4], bg[4];
#pragma unroll
            for (int mi = 0; mi < 4; mi++)
                af[mi].u4 = *(const u32x4*)&Al[(wr + mi * 16 + qc) * 64 + k2 * 32 + kg * 8];
#pragma unroll
            for (int ni = 0; ni < 4; ni++)
                bg[ni].u4 = *(const u32x4*)&Bl[(wc + ni * 16 + qc) * 64 + k2 * 32 + kg * 8];
#pragma unroll
            for (int mi = 0; mi < 4; mi++)
#pragma unroll
                for (int ni = 0; ni < 4; ni++)
                    acc[mi][ni] = __builtin_amdgcn_mfma_f32_16x16x32_bf16(
                        af[mi].b, bg[ni].b, acc[mi][ni], 0, 0, 0);
        }
    }
#pragma unroll
    for (int ni = 0; ni < 4; ni++) {
        int n = n0 + wc + ni * 16 + qc;
        float bval = bias[n];
        int h = n >> 6, hd = n & 63;
#pragma unroll
        for (int mi = 0; mi < 4; mi++) {
#pragma unroll
            for (int r = 0; r < 4; r++) {
                int m = m0 + wr + mi * 16 + kg * 4 + r;
                float v = (acc[mi][ni][r] + bval) * scale;
                int b = m >> 11, l = m & (LSEQ - 1);
                out[(((size_t)(b * NH + h)) * LSEQ + l) * HDIM + hd] = f2bf(v);
            }
        }
    }
}

// ---------------- O-projection GEMM: 128x64 tile (512 blocks, 2/CU) ----------------
__global__ __launch_bounds__(256) void gemm_o(
    const unsigned short* __restrict__ A, const unsigned short* __restrict__ Bt,
    const float* __restrict__ bias, float* __restrict__ outF)
{
    __shared__ unsigned short Al[128 * 64];
    __shared__ unsigned short Bl[64 * 64];
    int t = threadIdx.x;
    int lane = t & 63, w = t >> 6;
    int qc = lane & 15, kg = lane >> 4;
    int m0 = blockIdx.x * 128, n0 = blockIdx.y * 64;
    int wr = (w >> 1) * 64, wc = (w & 1) * 32;

    int srA = w * 32 + (lane >> 3);
    int srB = w * 16 + (lane >> 3);
    int scol = (lane & 7) * 8;
    const unsigned short* Ag = A + (size_t)(m0 + srA) * E_DIM + scol;
    const unsigned short* Bg = Bt + (size_t)(n0 + srB) * E_DIM + scol;
    unsigned short* Asl = &Al[(w * 32) * 64];
    unsigned short* Bsl = &Bl[(w * 16) * 64];

    f32x4 acc[4][2];
#pragma unroll
    for (int i = 0; i < 4; i++)
#pragma unroll
        for (int j = 0; j < 2; j++)
            acc[i][j] = {0.f, 0.f, 0.f, 0.f};

    for (int kt = 0; kt < E_DIM / 64; kt++) {
        const unsigned short* Ak = Ag + (kt << 6);
        const unsigned short* Bk = Bg + (kt << 6);
        __syncthreads();
#pragma unroll
        for (int i = 0; i < 4; i++)
            gload_lds16(Ak + (size_t)i * 8 * E_DIM, Asl + i * 8 * 64);
#pragma unroll
        for (int i = 0; i < 2; i++)
            gload_lds16(Bk + (size_t)i * 8 * E_DIM, Bsl + i * 8 * 64);
        __syncthreads();
#pragma unroll
        for (int k2 = 0; k2 < 2; k2++) {
            U16 af[4], bg[2];
#pragma unroll
            for (int mi = 0; mi < 4; mi++)
                af[mi].u4 = *(const u32x4*)&Al[(wr + mi * 16 + qc) * 64 + k2 * 32 + kg * 8];
#pragma unroll
            for (int ni = 0; ni < 2; ni++)
                bg[ni].u4 = *(const u32x4*)&Bl[(wc + ni * 16 + qc) * 64 + k2 * 32 + kg * 8];
#pragma unroll
            for (int mi = 0; mi < 4; mi++)
#pragma unroll
                for (int ni = 0; ni < 2; ni++)
                    acc[mi][ni] = __builtin_amdgcn_mfma_f32_16x16x32_bf16(
                        af[mi].b, bg[ni].b, acc[mi][ni], 0, 0, 0);
        }
    }
#pragma unroll
    for (int ni = 0; ni < 2; ni++) {
        int n = n0 + wc + ni * 16 + qc;
        float bval = bias[n];
#pragma unroll
        for (int mi = 0; mi < 4; mi++) {
#pragma unroll
            for (int r = 0; r < 4; r++) {
                int m = m0 + wr + mi * 16 + kg * 4 + r;
                outF[(size_t)m * E_DIM + n] = acc[mi][ni][r] + bval;
            }
        }
    }
}

// ---------------- causal flash attention: swapped operands, 8-wave balanced ----------------
// Qh/Kh: [bh][L][64] bf16 (Q pre-scaled by log2e/8). Vt: [bh][64][L] bf16.
// Grid (16, 32), 512 threads. Waves 0-3: q-tile x; waves 4-7: q-tile 31-x.
// S^T = mfma(K,Q): lane owns q-row = lane&15; softmax mostly in-register (2 shuffles).
// ctx^T = mfma(V^T, P^T): output col q = lane&15 matches softmax state.
__global__ __launch_bounds__(512, 4) void attn_causal(
    const unsigned short* __restrict__ Qh, const unsigned short* __restrict__ Kh,
    const unsigned short* __restrict__ Vt, unsigned short* __restrict__ Ctx)
{
    __shared__ unsigned short Pl[8][16][88];   // per-wave P buffer [q][kv], stride 176B
    // XCD-chunked remap (512 wgs, 8 XCDs): XCD k gets bh in [4k, 4k+4) -> K/V fit L2
    int flat_hw = blockIdx.y * 16 + blockIdx.x;
    int flat = (flat_hw & 7) * 64 + (flat_hw >> 3);
    int bh = flat >> 4;
    int xq = flat & 15;

    int t = threadIdx.x;
    int w = t >> 6, lane = t & 63;
    int qc = lane & 15, kg = lane >> 4;
    int qtile = (w < 4) ? xq : (31 - xq);
    int q0 = qtile * 64 + (w & 3) * 16;

    const unsigned short* Qb = Qh + (size_t)bh * LSEQ * HDIM;
    const unsigned short* Kp = Kh + (size_t)bh * LSEQ * HDIM + qc * HDIM + kg * 8;
    const unsigned short* Vbase = Vt + (size_t)bh * HDIM * LSEQ + qc * LSEQ + kg * 8;
    int b = bh >> 4, h = bh & 15;
    unsigned short* Cb = Ctx + ((size_t)b * LSEQ) * E_DIM + h * HDIM;

    unsigned short* Pw = &Pl[w][0][0];
    unsigned short* Pst = Pw + qc * 88 + kg * 4;        // store: row q=qc, col f*16+kg*4
    const unsigned short* Pld = Pw + qc * 88 + kg * 8;  // load B-frag: col q=qc, k=kv

    // Q as B-operand (col=q=lane&15, k=d=kg*8+j) — same addresses as before
    U16 qf0, qf1;
    qf0.u4 = *(const u32x4*)(Qb + (size_t)(q0 + qc) * HDIM + kg * 8);
    qf1.u4 = *(const u32x4*)(Qb + (size_t)(q0 + qc) * HDIM + 32 + kg * 8);

    f32x4 ctx[4];                 // ctx^T: d = df*16 + kg*4 + r, q = qc
#pragma unroll
    for (int df = 0; df < 4; df++) ctx[df] = {0.f, 0.f, 0.f, 0.f};
    float mrun = -1e30f, lrun = 0.f;

    int nt = (q0 + 16 + 63) >> 6;

    // preload K tile 0 as A-operand (row=kv=lane&15 within chunk, k=d)
    U16 kf[4][2];
#pragma unroll
    for (int f = 0; f < 4; f++) {
        kf[f][0].u4 = *(const u32x4*)(Kp + f * 16 * HDIM);
        kf[f][1].u4 = *(const u32x4*)(Kp + f * 16 * HDIM + 32);
    }

    for (int tt = 0; tt < nt; tt++) {
        int kv0 = tt << 6;
        // ---- S^T = K Q^T : s[f] rows kv = f*16+kg*4+r, col q = qc ----
        f32x4 s[4];
#pragma unroll
        for (int f = 0; f < 4; f++) {
            f32x4 z = {0.f, 0.f, 0.f, 0.f};
            z = __builtin_amdgcn_mfma_f32_16x16x32_bf16(kf[f][0].b, qf0.b, z, 0, 0, 0);
            z = __builtin_amdgcn_mfma_f32_16x16x32_bf16(kf[f][1].b, qf1.b, z, 0, 0, 0);
            s[f] = z;
        }
        // ---- V loads (A-op for ctx^T: row=d, k=kv) — independent of softmax ----
        U16 vf[2][4];
#pragma unroll
        for (int k2 = 0; k2 < 2; k2++)
#pragma unroll
            for (int df = 0; df < 4; df++)
                vf[k2][df].u4 = *(const u32x4*)(Vbase + (size_t)df * 16 * LSEQ +
                                                kv0 + k2 * 32);
        // ---- K prefetch for next tile (hides under softmax) ----
        if (tt + 1 < nt) {
            const unsigned short* Kt = Kp + (size_t)(kv0 + 64) * HDIM;
#pragma unroll
            for (int f = 0; f < 4; f++) {
                kf[f][0].u4 = *(const u32x4*)(Kt + f * 16 * HDIM);
                kf[f][1].u4 = *(const u32x4*)(Kt + f * 16 * HDIM + 32);
            }
        }
        // ---- causal mask (diagonal tiles only): kv = kv0+f*16+kg*4+r, q = q0+qc ----
        if (kv0 + 63 > q0) {
            int qi = q0 + qc;
#pragma unroll
            for (int f = 0; f < 4; f++) {
#pragma unroll
                for (int r = 0; r < 4; r++) {
                    if (kv0 + f * 16 + kg * 4 + r > qi) s[f][r] = -1e30f;
                }
            }
        }
        // ---- per-lane softmax over 16 regs + 2 cross-lane steps ----
        float m0_ = fmaxf(fmaxf(s[0][0], s[0][1]), fmaxf(s[0][2], s[0][3]));
        float m1_ = fmaxf(fmaxf(s[1][0], s[1][1]), fmaxf(s[1][2], s[1][3]));
        float m2_ = fmaxf(fmaxf(s[2][0], s[2][1]), fmaxf(s[2][2], s[2][3]));
        float m3_ = fmaxf(fmaxf(s[3][0], s[3][1]), fmaxf(s[3][2], s[3][3]));
        float tm = fmaxf(fmaxf(m0_, m1_), fmaxf(m2_, m3_));
        tm = fmaxf(tm, __shfl_xor(tm, 16));
        tm = fmaxf(tm, __shfl_xor(tm, 32));
        float mn;
        if (__all(tm - mrun <= 8.0f)) {       // T13 defer-max: skip rescale
            mn = mrun;
        } else {
            mn = fmaxf(mrun, tm);
            float sc = fexp2(mrun - mn);
            mrun = mn;
            lrun *= sc;
#pragma unroll
            for (int df = 0; df < 4; df++) ctx[df] *= sc;
        }
#pragma unroll
        for (int f = 0; f < 4; f++)
#pragma unroll
            for (int r = 0; r < 4; r++)
                s[f][r] = fexp2(s[f][r] - mn);
        float rs = ((s[0][0] + s[0][1]) + (s[0][2] + s[0][3]))
                 + ((s[1][0] + s[1][1]) + (s[1][2] + s[1][3]))
                 + ((s[2][0] + s[2][1]) + (s[2][2] + s[2][3]))
                 + ((s[3][0] + s[3][1]) + (s[3][2] + s[3][3]));
        rs += __shfl_xor(rs, 16);
        rs += __shfl_xor(rs, 32);
        lrun += rs;
        // ---- store P[q=qc][kv], 4x 8B chunks ----
#pragma unroll
        for (int f = 0; f < 4; f++) {
            u16x4 p = { f2bf(s[f][0]), f2bf(s[f][1]), f2bf(s[f][2]), f2bf(s[f][3]) };
            *(u16x4*)(Pst + f * 16) = p;
        }
        // ---- ctx^T += V^T P^T : A = V^T frag, B = P^T frag (col=q=qc, k=kv) ----
#pragma unroll
        for (int k2 = 0; k2 < 2; k2++) {
            U16 ap;
            ap.u4 = *(const u32x4*)(Pld + k2 * 32);
#pragma unroll
            for (int df = 0; df < 4; df++)
                ctx[df] = __builtin_amdgcn_mfma_f32_16x16x32_bf16(
                    vf[k2][df].b, ap.b, ctx[df], 0, 0, 0);
        }
    }
    // ---- normalize + store: lane holds q = q0+qc, d = df*16+kg*4+r ----
    float inv = 1.f / lrun;
    unsigned short* Cq = Cb + (size_t)(q0 + qc) * E_DIM;
#pragma unroll
    for (int df = 0; df < 4; df++) {
        u16x4 o = { f2bf(ctx[df][0] * inv), f2bf(ctx[df][1] * inv),
                    f2bf(ctx[df][2] * inv), f2bf(ctx[df][3] * inv) };
        *(u16x4*)(Cq + df * 16 + kg * 4) = o;
    }
}

// ---------------- launcher ----------------
extern "C" void kernel_launch(void* const* d_in, const int* in_sizes, int n_in,
                              void* d_out, int out_size, void* d_ws, size_t ws_size,
                              hipStream_t stream)
{
    (void)in_sizes; (void)n_in; (void)out_size; (void)ws_size;
    const float* query = (const float*)d_in[0];
    const float* key_  = (const float*)d_in[1];
    const float* value = (const float*)d_in[2];
    const float* Wq = (const float*)d_in[5];
    const float* bq = (const float*)d_in[6];
    const float* Wk = (const float*)d_in[7];
    const float* bk = (const float*)d_in[8];
    const float* Wv = (const float*)d_in[9];
    const float* bv = (const float*)d_in[10];
    const float* Wo = (const float*)d_in[11];
    const float* bo = (const float*)d_in[12];
    float* out = (float*)d_out;

    char* ws = (char*)d_ws;
    const size_t MB = 1024 * 1024;
    unsigned short* Xq  = (unsigned short*)(ws + 0 * MB);
    unsigned short* Xk  = (unsigned short*)(ws + 8 * MB);
    unsigned short* Xv  = (unsigned short*)(ws + 16 * MB);
    unsigned short* Wqt = (unsigned short*)(ws + 24 * MB);
    unsigned short* Wkt = (unsigned short*)(ws + 26 * MB);
    unsigned short* Wvt = (unsigned short*)(ws + 28 * MB);
    unsigned short* Wot = (unsigned short*)(ws + 30 * MB);
    unsigned short* Qh  = (unsigned short*)(ws + 32 * MB);
    unsigned short* Kh  = (unsigned short*)(ws + 40 * MB);
    unsigned short* Vh  = (unsigned short*)(ws + 48 * MB);
    unsigned short* Vtp = (unsigned short*)(ws + 56 * MB);
    unsigned short* Ctx = (unsigned short*)(ws + 0 * MB);  // reuse Xq

    const int nElem = MTOT * E_DIM;
    convert3<<<dim3(512, 3), 256, 0, stream>>>(query, key_, value, Xq, Xk, Xv, nElem);
    transpose_w4<<<dim3(16, 16, 4), 256, 0, stream>>>(Wq, Wk, Wv, Wo,
                                                      Wqt, Wkt, Wvt, Wot);

    const float SCALE_Q = 0.18033688011112042f;  // log2(e) / sqrt(HD)=8
    gemm_qkv<<<dim3(32, 8, 3), 256, 0, stream>>>(Xq, Xk, Xv, Wqt, Wkt, Wvt,
                                                 bq, bk, bv, Qh, Kh, Vh, SCALE_Q);

    transpose_v<<<dim3(32, 32), 256, 0, stream>>>(Vh, Vtp);

    attn_causal<<<dim3(16, 32), 512, 0, stream>>>(Qh, Kh, Vtp, Ctx);

    gemm_o<<<dim3(32, 16), 256, 0, stream>>>(Ctx, Wot, bo, out);
}

// Round 4
// 233.501 us; speedup vs baseline: 2.0056x; 1.3533x over previous
//
#include <hip/hip_runtime.h>

// Problem constants (fixed by the reference)
#define E_DIM 1024
#define NH    16
#define HDIM  64
#define BB    2
#define LSEQ  2048
#define MTOT  (BB*LSEQ)   // 4096 tokens

typedef float  f32x4  __attribute__((ext_vector_type(4)));
typedef __bf16 bf16x8 __attribute__((ext_vector_type(8)));
typedef unsigned int   u32x4 __attribute__((ext_vector_type(4)));
typedef unsigned short u16x4 __attribute__((ext_vector_type(4)));
typedef unsigned short u16x8 __attribute__((ext_vector_type(8)));

union U16 {           // 16-byte fragment: 8 bf16
    u32x4  u4;
    bf16x8 b;
};

__device__ inline unsigned short f2bf(float f) {
    union { __bf16 h; unsigned short u; } x;
    x.h = (__bf16)f;
    return x.u;
}

__device__ __forceinline__ float fexp2(float x) {
#if __has_builtin(__builtin_amdgcn_exp2f)
    return __builtin_amdgcn_exp2f(x);   // single v_exp_f32
#else
    return exp2f(x);
#endif
}

// async global->LDS, 16B per lane. LDS dest is wave-uniform base + lane*16.
__device__ __forceinline__ void gload_lds16(const unsigned short* g, unsigned short* l) {
    __builtin_amdgcn_global_load_lds(
        (const __attribute__((address_space(1))) void*)g,
        (__attribute__((address_space(3))) void*)l, 16, 0, 0);
}

// ---------------- fp32 -> bf16 bulk convert, 3 tensors in one launch ----------------
__global__ __launch_bounds__(256) void convert3(
    const float* __restrict__ q, const float* __restrict__ k, const float* __restrict__ v,
    unsigned short* __restrict__ Xq, unsigned short* __restrict__ Xk,
    unsigned short* __restrict__ Xv, int n)
{
    int z = blockIdx.y;
    const float* in = z == 0 ? q : (z == 1 ? k : v);
    unsigned short* out = z == 0 ? Xq : (z == 1 ? Xk : Xv);
    int i = (blockIdx.x * 256 + threadIdx.x) * 4;
    int stride = gridDim.x * 256 * 4;
    for (; i < n; i += stride) {
        f32x4 val = *(const f32x4*)(in + i);
        u16x4 o = { f2bf(val.x), f2bf(val.y), f2bf(val.z), f2bf(val.w) };
        *(u16x4*)(out + i) = o;
    }
}

// ---------------- W [K][N] f32 -> Wt [N][K] bf16, 4 weights in one launch ----------------
__global__ __launch_bounds__(256) void transpose_w4(
    const float* __restrict__ Wq, const float* __restrict__ Wk,
    const float* __restrict__ Wv, const float* __restrict__ Wo,
    unsigned short* __restrict__ Wqt, unsigned short* __restrict__ Wkt,
    unsigned short* __restrict__ Wvt, unsigned short* __restrict__ Wot)
{
    int z = blockIdx.z;
    const float* W = z == 0 ? Wq : (z == 1 ? Wk : (z == 2 ? Wv : Wo));
    unsigned short* Wt = z == 0 ? Wqt : (z == 1 ? Wkt : (z == 2 ? Wvt : Wot));
    __shared__ unsigned short tile[64][80];
    int n0 = blockIdx.x * 64, k0 = blockIdx.y * 64;
    int t = threadIdx.x;
#pragma unroll
    for (int i = 0; i < 4; i++) {
        int idx = i * 256 + t;
        int kr = idx >> 4, nc = (idx & 15) * 4;
        f32x4 val = *(const f32x4*)(W + (size_t)(k0 + kr) * E_DIM + n0 + nc);
        u16x4 o = { f2bf(val.x), f2bf(val.y), f2bf(val.z), f2bf(val.w) };
        *(u16x4*)&tile[kr][nc] = o;
    }
    __syncthreads();
#pragma unroll
    for (int i = 0; i < 2; i++) {
        int idx = i * 256 + t;
        int nr = idx >> 3, kc = (idx & 7) * 8;
        union { unsigned short s[8]; u16x8 v; } pack;
#pragma unroll
        for (int j = 0; j < 8; j++) pack.s[j] = tile[kc + j][nr];
        *(u16x8*)(Wt + (size_t)(n0 + nr) * E_DIM + k0 + kc) = pack.v;
    }
}

// ---------------- V [bh][L][64] -> Vt [bh][64][L] (bf16) ----------------
__global__ __launch_bounds__(256) void transpose_v(
    const unsigned short* __restrict__ V, unsigned short* __restrict__ Vt)
{
    __shared__ unsigned short tile[64][80];
    int l0 = blockIdx.x * 64;
    int bh = blockIdx.y;
    const unsigned short* Vb = V + (size_t)bh * LSEQ * HDIM;
    unsigned short* Vtb = Vt + (size_t)bh * HDIM * LSEQ;
    int t = threadIdx.x;
#pragma unroll
    for (int i = 0; i < 2; i++) {
        int idx = i * 256 + t;
        int lr = idx >> 3, dc = (idx & 7) * 8;
        *(u16x8*)&tile[lr][dc] = *(const u16x8*)(Vb + (size_t)(l0 + lr) * HDIM + dc);
    }
    __syncthreads();
#pragma unroll
    for (int i = 0; i < 2; i++) {
        int idx = i * 256 + t;
        int dr = idx >> 3, lc = (idx & 7) * 8;
        union { unsigned short s[8]; u16x8 v; } pack;
#pragma unroll
        for (int j = 0; j < 8; j++) pack.s[j] = tile[lc + j][dr];
        *(u16x8*)(Vtb + (size_t)dr * LSEQ + l0 + lc) = pack.v;
    }
}

// ---------------- batched QKV projection GEMM (z = 0,1,2) ----------------
__global__ __launch_bounds__(256) void gemm_qkv(
    const unsigned short* __restrict__ Xq, const unsigned short* __restrict__ Xk,
    const unsigned short* __restrict__ Xv,
    const unsigned short* __restrict__ Wqt, const unsigned short* __restrict__ Wkt,
    const unsigned short* __restrict__ Wvt,
    const float* __restrict__ bqp, const float* __restrict__ bkp, const float* __restrict__ bvp,
    unsigned short* __restrict__ Qh, unsigned short* __restrict__ Kh,
    unsigned short* __restrict__ Vh, float scaleQ)
{
    int z = blockIdx.z;
    const unsigned short* A  = z == 0 ? Xq  : (z == 1 ? Xk  : Xv);
    const unsigned short* Bt = z == 0 ? Wqt : (z == 1 ? Wkt : Wvt);
    const float* bias        = z == 0 ? bqp : (z == 1 ? bkp : bvp);
    unsigned short* out      = z == 0 ? Qh  : (z == 1 ? Kh  : Vh);
    float scale              = z == 0 ? scaleQ : 1.0f;

    __shared__ unsigned short Al[128 * 64];
    __shared__ unsigned short Bl[128 * 64];
    int t = threadIdx.x;
    int lane = t & 63, w = t >> 6;
    int qc = lane & 15, kg = lane >> 4;
    int m0 = blockIdx.x * 128, n0 = blockIdx.y * 128;
    int wr = (w >> 1) * 64, wc = (w & 1) * 64;

    int srow = w * 32 + (lane >> 3);
    int scol = (lane & 7) * 8;
    const unsigned short* Ag = A + (size_t)(m0 + srow) * E_DIM + scol;
    const unsigned short* Bg = Bt + (size_t)(n0 + srow) * E_DIM + scol;
    unsigned short* Asl = &Al[(w * 32) * 64];
    unsigned short* Bsl = &Bl[(w * 32) * 64];

    f32x4 acc[4][4];
#pragma unroll
    for (int i = 0; i < 4; i++)
#pragma unroll
        for (int j = 0; j < 4; j++)
            acc[i][j] = {0.f, 0.f, 0.f, 0.f};

    for (int kt = 0; kt < E_DIM / 64; kt++) {
        const unsigned short* Ak = Ag + (kt << 6);
        const unsigned short* Bk = Bg + (kt << 6);
        __syncthreads();
#pragma unroll
        for (int i = 0; i < 4; i++) {
            gload_lds16(Ak + (size_t)i * 8 * E_DIM, Asl + i * 8 * 64);
            gload_lds16(Bk + (size_t)i * 8 * E_DIM, Bsl + i * 8 * 64);
        }
        __syncthreads();
#pragma unroll
        for (int k2 = 0; k2 < 2; k2++) {
            U16 af[4], bg[4];
#pragma unroll
            for (int mi = 0; mi < 4; mi++)
                af[mi].u4 = *(const u32x4*)&Al[(wr + mi * 16 + qc) * 64 + k2 * 32 + kg * 8];
#pragma unroll
            for (int ni = 0; ni < 4; ni++)
                bg[ni].u4 = *(const u32x4*)&Bl[(wc + ni * 16 + qc) * 64 + k2 * 32 + kg * 8];
#pragma unroll
            for (int mi = 0; mi < 4; mi++)
#pragma unroll
                for (int ni = 0; ni < 4; ni++)
                    acc[mi][ni] = __builtin_amdgcn_mfma_f32_16x16x32_bf16(
                        af[mi].b, bg[ni].b, acc[mi][ni], 0, 0, 0);
        }
    }
#pragma unroll
    for (int ni = 0; ni < 4; ni++) {
        int n = n0 + wc + ni * 16 + qc;
        float bval = bias[n];
        int h = n >> 6, hd = n & 63;
#pragma unroll
        for (int mi = 0; mi < 4; mi++) {
#pragma unroll
            for (int r = 0; r < 4; r++) {
                int m = m0 + wr + mi * 16 + kg * 4 + r;
                float v = (acc[mi][ni][r] + bval) * scale;
                int b = m >> 11, l = m & (LSEQ - 1);
                out[(((size_t)(b * NH + h)) * LSEQ + l) * HDIM + hd] = f2bf(v);
            }
        }
    }
}

// ---------------- O-projection GEMM: 128x64 tile ----------------
__global__ __launch_bounds__(256) void gemm_o(
    const unsigned short* __restrict__ A, const unsigned short* __restrict__ Bt,
    const float* __restrict__ bias, float* __restrict__ outF)
{
    __shared__ unsigned short Al[128 * 64];
    __shared__ unsigned short Bl[64 * 64];
    int t = threadIdx.x;
    int lane = t & 63, w = t >> 6;
    int qc = lane & 15, kg = lane >> 4;
    int m0 = blockIdx.x * 128, n0 = blockIdx.y * 64;
    int wr = (w >> 1) * 64, wc = (w & 1) * 32;

    int srA = w * 32 + (lane >> 3);
    int srB = w * 16 + (lane >> 3);
    int scol = (lane & 7) * 8;
    const unsigned short* Ag = A + (size_t)(m0 + srA) * E_DIM + scol;
    const unsigned short* Bg = Bt + (size_t)(n0 + srB) * E_DIM + scol;
    unsigned short* Asl = &Al[(w * 32) * 64];
    unsigned short* Bsl = &Bl[(w * 16) * 64];

    f32x4 acc[4][2];
#pragma unroll
    for (int i = 0; i < 4; i++)
#pragma unroll
        for (int j = 0; j < 2; j++)
            acc[i][j] = {0.f, 0.f, 0.f, 0.f};

    for (int kt = 0; kt < E_DIM / 64; kt++) {
        const unsigned short* Ak = Ag + (kt << 6);
        const unsigned short* Bk = Bg + (kt << 6);
        __syncthreads();
#pragma unroll
        for (int i = 0; i < 4; i++)
            gload_lds16(Ak + (size_t)i * 8 * E_DIM, Asl + i * 8 * 64);
#pragma unroll
        for (int i = 0; i < 2; i++)
            gload_lds16(Bk + (size_t)i * 8 * E_DIM, Bsl + i * 8 * 64);
        __syncthreads();
#pragma unroll
        for (int k2 = 0; k2 < 2; k2++) {
            U16 af[4], bg[2];
#pragma unroll
            for (int mi = 0; mi < 4; mi++)
                af[mi].u4 = *(const u32x4*)&Al[(wr + mi * 16 + qc) * 64 + k2 * 32 + kg * 8];
#pragma unroll
            for (int ni = 0; ni < 2; ni++)
                bg[ni].u4 = *(const u32x4*)&Bl[(wc + ni * 16 + qc) * 64 + k2 * 32 + kg * 8];
#pragma unroll
            for (int mi = 0; mi < 4; mi++)
#pragma unroll
                for (int ni = 0; ni < 2; ni++)
                    acc[mi][ni] = __builtin_amdgcn_mfma_f32_16x16x32_bf16(
                        af[mi].b, bg[ni].b, acc[mi][ni], 0, 0, 0);
        }
    }
#pragma unroll
    for (int ni = 0; ni < 2; ni++) {
        int n = n0 + wc + ni * 16 + qc;
        float bval = bias[n];
#pragma unroll
        for (int mi = 0; mi < 4; mi++) {
#pragma unroll
            for (int r = 0; r < 4; r++) {
                int m = m0 + wr + mi * 16 + kg * 4 + r;
                outF[(size_t)m * E_DIM + n] = acc[mi][ni][r] + bval;
            }
        }
    }
}

// ---------------- causal flash attention: block-cooperative LDS-staged ----------------
// Qh/Kh: [bh][L][64] bf16 (Q pre-scaled by log2e/8). Vt: [bh][64][L] bf16.
// Grid 256 linear, 512 threads (8 waves). Block owns bh = flat>>3 and processes
// q-blocks qb = pr (pass 0) and 15-pr (pass 1), 128 rows each; wave w gets 16 rows.
// K/V kv-tiles (64x64 bf16, 8KB) staged once per block via global_load_lds into
// double-buffered swizzled LDS (pre-swizzled global source, swizzled ds_read).
// Swapped-operand MFMA: S^T = K.Q^T, ctx^T = V^T.P^T; per-lane softmax.
__global__ __launch_bounds__(512, 2) void attn_causal(
    const unsigned short* __restrict__ Qh, const unsigned short* __restrict__ Kh,
    const unsigned short* __restrict__ Vt, unsigned short* __restrict__ Ctx)
{
    __shared__ unsigned short Kst[2][64 * 64];   // [kv][d], swizzled, 8KB/buf
    __shared__ unsigned short Vst[2][64 * 64];   // [d][kv], swizzled, 8KB/buf
    __shared__ unsigned short Pl[8][16 * 72];    // per-wave P[q][kv], stride 72

    // XCD chunking: XCD k gets flat in [32k,32k+32) -> bh in [4k,4k+4): K/V fit L2
    int flat_hw = blockIdx.x;
    int flat = (flat_hw & 7) * 32 + (flat_hw >> 3);
    int bh = flat >> 3;          // 0..31
    int pr = flat & 7;           // pair id: q-blocks pr and 15-pr

    int t = threadIdx.x;
    int w = t >> 6, lane = t & 63;
    int qc = lane & 15, kg = lane >> 4;

    const unsigned short* Qb  = Qh + (size_t)bh * LSEQ * HDIM;
    const unsigned short* Kb  = Kh + (size_t)bh * LSEQ * HDIM;
    const unsigned short* Vbt = Vt + (size_t)bh * HDIM * LSEQ;
    int b = bh >> 4, h = bh & 15;
    unsigned short* Cb = Ctx + ((size_t)b * LSEQ) * E_DIM + h * HDIM;

    // staging lane constants: lane stages 16B of row (8w+lrow), swizzled col
    int lrow = lane >> 3;                      // 0..7
    int c16s = ((lane & 7) ^ lrow) * 8;        // pre-swizzled source col (elems)
    int krow = 8 * w + lrow;                   // tile-local row this lane stages
    unsigned short* KstW0 = &Kst[0][w * 512];  // wave-uniform LDS bases
    unsigned short* KstW1 = &Kst[1][w * 512];
    unsigned short* VstW0 = &Vst[0][w * 512];
    unsigned short* VstW1 = &Vst[1][w * 512];

    unsigned short* Pw = &Pl[w][0];
    unsigned short* Pst = Pw + qc * 72 + kg * 4;        // store: row q=qc, col f*16+kg*4
    const unsigned short* Pld = Pw + qc * 72 + kg * 8;  // load B-frag: col q=qc, k=kv

    int sw = (qc & 7) * 8;   // read-side swizzle term for row qc within 16-row frags

    for (int pass = 0; pass < 2; pass++) {
        int qb = pass ? (15 - pr) : pr;       // q-block 0..15 (128 rows)
        int q0w = qb * 128 + w * 16;          // this wave's first q row
        int nt = 2 * qb + 2;                  // kv tiles for the block (uniform)
        int nta = (q0w + 79) >> 6;            // active tiles for this wave

        // Q B-frags (col=q=lane&15, k=d=kg*8+j)
        U16 qf0, qf1;
        qf0.u4 = *(const u32x4*)(Qb + (size_t)(q0w + qc) * HDIM + kg * 8);
        qf1.u4 = *(const u32x4*)(Qb + (size_t)(q0w + qc) * HDIM + 32 + kg * 8);

        f32x4 ctx[4];
#pragma unroll
        for (int df = 0; df < 4; df++) ctx[df] = {0.f, 0.f, 0.f, 0.f};
        float mrun = -1e30f, lrun = 0.f;

        // prologue: stage tile 0 into buffer 0
        gload_lds16(Kb + (size_t)krow * HDIM + c16s, KstW0);
        gload_lds16(Vbt + (size_t)krow * LSEQ + c16s, VstW0);
        __syncthreads();   // drains vmcnt: tile 0 visible

        for (int tt = 0; tt < nt; tt++) {
            int kv0 = tt << 6;
            int cur = tt & 1;
            // stage next tile into the other buffer (async; drains at barrier)
            if (tt + 1 < nt) {
                int kvn = kv0 + 64;
                gload_lds16(Kb + (size_t)(kvn + krow) * HDIM + c16s,
                            cur ? KstW0 : KstW1);
                gload_lds16(Vbt + (size_t)krow * LSEQ + kvn + c16s,
                            cur ? VstW0 : VstW1);
            }
            if (tt < nta) {
                const unsigned short* Kc = &Kst[cur][0];
                const unsigned short* Vc = &Vst[cur][0];
                // ---- S^T = K Q^T : rows kv = f*16+kg*4+r, col q = qc ----
                f32x4 s[4];
#pragma unroll
                for (int f = 0; f < 4; f++) {
                    U16 k0_, k1_;   // A-frag row kv=f*16+qc, k=d (2 halves)
                    k0_.u4 = *(const u32x4*)&Kc[(f * 16 + qc) * 64 + ((kg * 8) ^ sw)];
                    k1_.u4 = *(const u32x4*)&Kc[(f * 16 + qc) * 64 + ((32 + kg * 8) ^ sw)];
                    f32x4 z = {0.f, 0.f, 0.f, 0.f};
                    z = __builtin_amdgcn_mfma_f32_16x16x32_bf16(k0_.b, qf0.b, z, 0, 0, 0);
                    z = __builtin_amdgcn_mfma_f32_16x16x32_bf16(k1_.b, qf1.b, z, 0, 0, 0);
                    s[f] = z;
                }
                // ---- causal mask (diagonal tiles only) ----
                if (kv0 + 63 > q0w) {
                    int qi = q0w + qc;
#pragma unroll
                    for (int f = 0; f < 4; f++) {
#pragma unroll
                        for (int r = 0; r < 4; r++) {
                            if (kv0 + f * 16 + kg * 4 + r > qi) s[f][r] = -1e30f;
                        }
                    }
                }
                // ---- per-lane softmax (16 regs) + 2 cross-lane steps ----
                float m0_ = fmaxf(fmaxf(s[0][0], s[0][1]), fmaxf(s[0][2], s[0][3]));
                float m1_ = fmaxf(fmaxf(s[1][0], s[1][1]), fmaxf(s[1][2], s[1][3]));
                float m2_ = fmaxf(fmaxf(s[2][0], s[2][1]), fmaxf(s[2][2], s[2][3]));
                float m3_ = fmaxf(fmaxf(s[3][0], s[3][1]), fmaxf(s[3][2], s[3][3]));
                float tm = fmaxf(fmaxf(m0_, m1_), fmaxf(m2_, m3_));
                tm = fmaxf(tm, __shfl_xor(tm, 16));
                tm = fmaxf(tm, __shfl_xor(tm, 32));
                float mn;
                if (__all(tm - mrun <= 8.0f)) {       // T13 defer-max
                    mn = mrun;
                } else {
                    mn = fmaxf(mrun, tm);
                    float sc = fexp2(mrun - mn);
                    mrun = mn;
                    lrun *= sc;
#pragma unroll
                    for (int df = 0; df < 4; df++) ctx[df] *= sc;
                }
#pragma unroll
                for (int f = 0; f < 4; f++)
#pragma unroll
                    for (int r = 0; r < 4; r++)
                        s[f][r] = fexp2(s[f][r] - mn);
                float rs = ((s[0][0] + s[0][1]) + (s[0][2] + s[0][3]))
                         + ((s[1][0] + s[1][1]) + (s[1][2] + s[1][3]))
                         + ((s[2][0] + s[2][1]) + (s[2][2] + s[2][3]))
                         + ((s[3][0] + s[3][1]) + (s[3][2] + s[3][3]));
                rs += __shfl_xor(rs, 16);
                rs += __shfl_xor(rs, 32);
                lrun += rs;
                // ---- store P[q=qc][kv] ----
#pragma unroll
                for (int f = 0; f < 4; f++) {
                    u16x4 p = { f2bf(s[f][0]), f2bf(s[f][1]), f2bf(s[f][2]), f2bf(s[f][3]) };
                    *(u16x4*)(Pst + f * 16) = p;
                }
                // ---- ctx^T += V^T P^T ----
#pragma unroll
                for (int k2 = 0; k2 < 2; k2++) {
                    U16 ap;
                    ap.u4 = *(const u32x4*)(Pld + k2 * 32);
#pragma unroll
                    for (int df = 0; df < 4; df++) {
                        U16 vf;   // A-frag row d=df*16+qc, k=kv (half k2)
                        vf.u4 = *(const u32x4*)&Vc[(df * 16 + qc) * 64 +
                                                   ((k2 * 32 + kg * 8) ^ sw)];
                        ctx[df] = __builtin_amdgcn_mfma_f32_16x16x32_bf16(
                            vf.b, ap.b, ctx[df], 0, 0, 0);
                    }
                }
            }
            __syncthreads();   // drains staging vmcnt + separates buffers
        }
        // ---- normalize + store: lane holds q = q0w+qc, d = df*16+kg*4+r ----
        float inv = 1.f / lrun;
        unsigned short* Cq = Cb + (size_t)(q0w + qc) * E_DIM;
#pragma unroll
        for (int df = 0; df < 4; df++) {
            u16x4 o = { f2bf(ctx[df][0] * inv), f2bf(ctx[df][1] * inv),
                        f2bf(ctx[df][2] * inv), f2bf(ctx[df][3] * inv) };
            *(u16x4*)(Cq + df * 16 + kg * 4) = o;
        }
        // loop's final __syncthreads already separates pass 0 readers from
        // pass 1's prologue staging
    }
}

// ---------------- launcher ----------------
extern "C" void kernel_launch(void* const* d_in, const int* in_sizes, int n_in,
                              void* d_out, int out_size, void* d_ws, size_t ws_size,
                              hipStream_t stream)
{
    (void)in_sizes; (void)n_in; (void)out_size; (void)ws_size;
    const float* query = (const float*)d_in[0];
    const float* key_  = (const float*)d_in[1];
    const float* value = (const float*)d_in[2];
    const float* Wq = (const float*)d_in[5];
    const float* bq = (const float*)d_in[6];
    const float* Wk = (const float*)d_in[7];
    const float* bk = (const float*)d_in[8];
    const float* Wv = (const float*)d_in[9];
    const float* bv = (const float*)d_in[10];
    const float* Wo = (const float*)d_in[11];
    const float* bo = (const float*)d_in[12];
    float* out = (float*)d_out;

    char* ws = (char*)d_ws;
    const size_t MB = 1024 * 1024;
    unsigned short* Xq  = (unsigned short*)(ws + 0 * MB);
    unsigned short* Xk  = (unsigned short*)(ws + 8 * MB);
    unsigned short* Xv  = (unsigned short*)(ws + 16 * MB);
    unsigned short* Wqt = (unsigned short*)(ws + 24 * MB);
    unsigned short* Wkt = (unsigned short*)(ws + 26 * MB);
    unsigned short* Wvt = (unsigned short*)(ws + 28 * MB);
    unsigned short* Wot = (unsigned short*)(ws + 30 * MB);
    unsigned short* Qh  = (unsigned short*)(ws + 32 * MB);
    unsigned short* Kh  = (unsigned short*)(ws + 40 * MB);
    unsigned short* Vh  = (unsigned short*)(ws + 48 * MB);
    unsigned short* Vtp = (unsigned short*)(ws + 56 * MB);
    unsigned short* Ctx = (unsigned short*)(ws + 0 * MB);  // reuse Xq

    const int nElem = MTOT * E_DIM;
    convert3<<<dim3(512, 3), 256, 0, stream>>>(query, key_, value, Xq, Xk, Xv, nElem);
    transpose_w4<<<dim3(16, 16, 4), 256, 0, stream>>>(Wq, Wk, Wv, Wo,
                                                      Wqt, Wkt, Wvt, Wot);

    const float SCALE_Q = 0.18033688011112042f;  // log2(e) / sqrt(HD)=8
    gemm_qkv<<<dim3(32, 8, 3), 256, 0, stream>>>(Xq, Xk, Xv, Wqt, Wkt, Wvt,
                                                 bq, bk, bv, Qh, Kh, Vh, SCALE_Q);

    transpose_v<<<dim3(32, 32), 256, 0, stream>>>(Vh, Vtp);

    attn_causal<<<dim3(256), 512, 0, stream>>>(Qh, Kh, Vtp, Ctx);

    gemm_o<<<dim3(32, 16), 256, 0, stream>>>(Ctx, Wot, bo, out);
}